// Round 18
// baseline (154.424 us; speedup 1.0000x reference)
//
#include <hip/hip_runtime.h>
#include <stdint.h>

typedef __attribute__((ext_vector_type(8))) short bf16x8;
typedef __attribute__((ext_vector_type(4))) float f32x4;
typedef __attribute__((ext_vector_type(2))) unsigned u32x2;

#define MFMA16(a,b,c) __builtin_amdgcn_mfma_f32_16x16x32_bf16(a,b,c,0,0,0)

typedef const __attribute__((address_space(1))) void GV;
typedef __attribute__((address_space(3))) void LV;

static __device__ __forceinline__ void gload16(const void* g, void* l) {
  __builtin_amdgcn_global_load_lds((GV*)g, (LV*)l, 16, 0, 0);
}

static __device__ __forceinline__ unsigned short f2bf(float f) {
  union { float f; unsigned u; } x; x.f = f;
  unsigned r = x.u + 0x7FFFu + ((x.u >> 16) & 1u);
  return (unsigned short)(r >> 16);
}

static __device__ __forceinline__ float fast_exp2(float x) {
#if __has_builtin(__builtin_amdgcn_exp2f)
  return __builtin_amdgcn_exp2f(x);
#else
  return __expf(x * 0.6931471805599453f);
#endif
}

// ---------------- pack: x -> bf16, weights -> transposed bf16 (all coalesced) ----------------
__global__ __launch_bounds__(256) void pack_all(
    const float* __restrict__ x, const float* __restrict__ Wq,
    const float* __restrict__ Wkv, const float* __restrict__ Wp,
    const float* __restrict__ Wsr,
    unsigned short* __restrict__ xb, unsigned short* __restrict__ wqt,
    unsigned short* __restrict__ wkvt, unsigned short* __restrict__ wpt,
    unsigned short* __restrict__ wsrt) {
  const int tid = threadIdx.x;
  int bid = blockIdx.x;
  if (bid < 16384) {                      // x -> bf16, 4 floats/thread
    int i = bid * 256 + tid;
    float4 v = ((const float4*)x)[i];
    unsigned a0 = f2bf(v.x), a1 = f2bf(v.y), a2 = f2bf(v.z), a3 = f2bf(v.w);
    uint2 pk; pk.x = a0 | (a1 << 16); pk.y = a2 | (a3 << 16);
    ((uint2*)xb)[i] = pk;
    return;
  }
  bid -= 16384;
  __shared__ float lsm[8704];             // 64x65 tiles / 512x17 for Wsr

  auto wtile = [&](const float* __restrict__ W, unsigned short* __restrict__ out,
                   int ldw, int tr, int tc) {
    int k0 = tr * 64, n0 = tc * 64;
    #pragma unroll
    for (int i = 0; i < 16; ++i) {
      int idx = i * 256 + tid; int r = idx >> 6, c = idx & 63;
      lsm[r * 65 + c] = W[(size_t)(k0 + r) * ldw + n0 + c];
    }
    __syncthreads();
    #pragma unroll
    for (int i = 0; i < 16; ++i) {
      int idx = i * 256 + tid; int n = idx >> 6, k = idx & 63;
      out[(size_t)(n0 + n) * 512 + k0 + k] = f2bf(lsm[k * 65 + n]);
    }
  };

  if (bid < 64) { wtile(Wq, wqt, 512, bid >> 3, bid & 7); return; }
  bid -= 64;
  if (bid < 128) { wtile(Wkv, wkvt, 1024, bid >> 4, bid & 15); return; }
  bid -= 128;
  if (bid < 64) { wtile(Wp, wpt, 512, bid >> 3, bid & 7); return; }
  bid -= 64;
  // Wsr: per oc, transpose [ic(512)][r12(16)] -> wsrt[oc][r12][ic]
  int oc = bid;
  #pragma unroll
  for (int i = 0; i < 32; ++i) {
    int idx = i * 256 + tid;
    lsm[(idx >> 4) * 17 + (idx & 15)] = Wsr[(size_t)oc * 8192 + idx];
  }
  __syncthreads();
  #pragma unroll
  for (int i = 0; i < 32; ++i) {
    int idx = i * 256 + tid;                      // idx = r12*512 + ic
    int ic = idx & 511, r12 = idx >> 9;
    wsrt[(size_t)oc * 8192 + idx] = f2bf(lsm[ic * 17 + r12]);
  }
}

// ---------------- 8-wave GEMM body: 128x128 tile, A-dbuf / B-single ----------------
// LDS 48KB -> 3 blocks/CU = 24 waves/CU (TLP covers B latency, m114).
// A double-buffered with counted vmcnt(2); B restaged each step after the
// barrier that retires its readers. 512 thr = 8 waves (2M x 4N), acc[4][2].
// MODE 0: fp32 out (+bias); MODE 2: K/V scatter; MODE 3: conv partial;
// MODE 4: Q fragment scatter (+bias, * 0.125*log2e)
template<int MODE, bool CONV>
static __device__ __forceinline__ void gemm8_body(
    unsigned short* lds_a, unsigned short* lds_b,
    const unsigned short* __restrict__ A, const unsigned short* __restrict__ Bt,
    const float* __restrict__ bias, void* __restrict__ outp,
    unsigned short* __restrict__ out_k, unsigned short* __restrict__ out_v,
    int M, int N, int K, int lda, int Ksub, int m0, int n0, int kbeg, int zslice) {
  constexpr int BK = 64;
  constexpr int ABYTES = 128 * BK * 2;     // 16 KB per buffer
  const int tid = threadIdx.x;
  const int lane = tid & 63, w = tid >> 6;
  const int wr = w >> 2, wc = w & 3;       // 2 x 4 wave grid
  const int l15 = lane & 15, lhi = lane >> 4;
  const int xmask = (l15 & 7) << 4;        // read-side byte swizzle
  const int smask = ((tid >> 3) & 7) << 3; // stage-side element swizzle

  f32x4 acc[4][2] = {};

  auto stageA = [&](int buf, int k0) {
    #pragma unroll
    for (int r = 0; r < 2; ++r) {
      int o = r * 8192 + tid * 16;
      int row = o >> 7;
      int kc = (((o & 127) >> 1)) ^ smask;
      const unsigned short* src;
      if constexpr (CONV) {
        int m = m0 + row;
        int bb = m >> 8, pix = m & 255;
        int oh = pix >> 4, ow = pix & 15;
        int r12 = k0 >> 9;
        int icc = (k0 & 511) + kc;
        int r1 = r12 >> 2, r2 = r12 & 3;
        int nn = (oh * 4 + r1) * 64 + ow * 4 + r2;
        src = A + ((size_t)(bb * 4096 + nn)) * 512 + icc;
      } else {
        src = A + (size_t)(m0 + row) * lda + k0 + kc;
      }
      gload16(src, (char*)lds_a + buf * ABYTES + r * 8192 + w * 1024);
    }
  };
  auto stageB = [&](int k0) {
    #pragma unroll
    for (int r = 0; r < 2; ++r) {
      int o = r * 8192 + tid * 16;
      int row = o >> 7;
      int kc = (((o & 127) >> 1)) ^ smask;
      const unsigned short* src = Bt + (size_t)(n0 + row) * K + k0 + kc;
      gload16(src, (char*)lds_b + r * 8192 + w * 1024);
    }
  };

  auto compute = [&](int ab) {
    const char* pa = (const char*)lds_a + ab * ABYTES;
    const char* pb = (const char*)lds_b;
    #pragma unroll
    for (int kk = 0; kk < BK; kk += 32) {
      bf16x8 af[4], bfr[2];
      #pragma unroll
      for (int m = 0; m < 4; ++m)
        af[m] = *(const bf16x8*)(pa + (wr * 64 + m * 16 + l15) * 128
                                 + (((kk << 1) + (lhi << 4)) ^ xmask));
      #pragma unroll
      for (int n = 0; n < 2; ++n)
        bfr[n] = *(const bf16x8*)(pb + (wc * 32 + n * 16 + l15) * 128
                                  + (((kk << 1) + (lhi << 4)) ^ xmask));
      __builtin_amdgcn_s_setprio(1);
      #pragma unroll
      for (int m = 0; m < 4; ++m)
        #pragma unroll
        for (int n = 0; n < 2; ++n)
          acc[m][n] = MFMA16(af[m], bfr[n], acc[m][n]);
      __builtin_amdgcn_s_setprio(0);
    }
  };

  const int nsteps = Ksub / BK;
  stageA(0, kbeg);
  int buf = 0;
  for (int t = 0; t < nsteps; ++t) {
    stageB(kbeg + t * BK);                 // B buffer freed by prev closing barrier
    if (t + 1 < nsteps) {
      stageA(buf ^ 1, kbeg + (t + 1) * BK);
      asm volatile("s_waitcnt vmcnt(2)" ::: "memory");  // A(t),B(t) landed; A(t+1) in flight
    } else {
      asm volatile("s_waitcnt vmcnt(0)" ::: "memory");
    }
    __builtin_amdgcn_s_barrier();
    compute(buf);
    __builtin_amdgcn_s_barrier();          // retires B readers before next stageB
    buf ^= 1;
  }

  #pragma unroll
  for (int m = 0; m < 4; ++m) {
    #pragma unroll
    for (int n = 0; n < 2; ++n) {
      #pragma unroll
      for (int r = 0; r < 4; ++r) {
        int gm = m0 + wr * 64 + m * 16 + lhi * 4 + r;
        int gn = n0 + wc * 32 + n * 16 + l15;
        if constexpr (MODE == 0) {
          ((float*)outp)[(size_t)gm * N + gn] = acc[m][n][r] + bias[gn];
        } else if constexpr (MODE == 3) {
          ((float*)outp)[((size_t)zslice * M + gm) * N + gn] = acc[m][n][r];
        } else if constexpr (MODE == 4) {
          float v = (acc[m][n][r] + bias[gn]) * 0.18033688011112042f;  // 0.125*log2(e)
          int b_ = gm >> 12, n_ = gm & 4095;
          int hh = gn >> 6, d = gn & 63;
          int qt = n_ >> 4, half = d >> 5, dd = d & 31;
          int ln = (n_ & 15) | ((dd >> 3) << 4);
          ((unsigned short*)outp)[(size_t)(b_ * 8 + hh) * 262144 +
              (qt * 2 + half) * 512 + ln * 8 + (d & 7)] = f2bf(v);
        } else {  // MODE 2: K/V scatter
          float v = acc[m][n][r] + bias[gn];
          unsigned short bv = f2bf(v);
          int bb = gm >> 8, nr = gm & 255;
          if (gn < 512) {
            int hh = gn >> 6, d = gn & 63;
            int t_ = nr >> 4, half = d >> 5, dd = d & 31;
            int ln = (nr & 15) | ((dd >> 3) << 4);
            out_k[(size_t)(bb * 8 + hh) * 16384 +
                  (t_ * 2 + half) * 512 + ln * 8 + (d & 7)] = bv;
          } else {
            int c = gn - 512;
            int hh = c >> 6, d = c & 63;
            int nn = d >> 4, cl = d & 15;
            int ks = nr >> 5, lh = (nr >> 3) & 3;
            out_v[(size_t)(bb * 8 + hh) * 16384 +
                  (nn * 8 + ks) * 512 + (cl | (lh << 4)) * 8 + (nr & 7)] = bv;
          }
        }
      }
    }
  }
}

// standalone 8-wave GEMM kernel, optional XCD swizzle (LDS: A x2 + B x1 = 48KB)
template<int MODE, bool CONV, bool SWZ>
__global__ __launch_bounds__(512, 4) void gemm8(
    const unsigned short* __restrict__ A, const unsigned short* __restrict__ Bt,
    const float* __restrict__ bias, void* __restrict__ outp,
    unsigned short* __restrict__ out_k, unsigned short* __restrict__ out_v,
    int M, int N, int K, int lda, int Ksub) {
  __shared__ unsigned short lds_a[2 * 128 * 64];
  __shared__ unsigned short lds_b[1 * 128 * 64];
  int mt, nt_;
  if constexpr (SWZ) {
    int lin = blockIdx.x + blockIdx.y * gridDim.x;
    int nwg = gridDim.x * gridDim.y;
    int cpx = nwg >> 3;
    int s = (lin & 7) * cpx + (lin >> 3);
    int gdy = gridDim.y;
    mt = s / gdy; nt_ = s - mt * gdy;
  } else { mt = blockIdx.x; nt_ = blockIdx.y; }
  gemm8_body<MODE, CONV>(lds_a, lds_b, A, Bt, bias, outp, out_k, out_v,
                         M, N, K, lda, Ksub, mt * 128, nt_ * 128,
                         blockIdx.z * Ksub, blockIdx.z);
}

// fused Q-proj (1024 blocks, swizzled) + KV-proj (128 blocks), 8-wave
__global__ __launch_bounds__(512, 4) void proj_fused(
    const unsigned short* __restrict__ xb, const unsigned short* __restrict__ wqt,
    const float* __restrict__ bq, unsigned short* __restrict__ qfrag,
    const unsigned short* __restrict__ xln, const unsigned short* __restrict__ wkvt,
    const float* __restrict__ bkv, unsigned short* __restrict__ kfrag,
    unsigned short* __restrict__ vfrag) {
  __shared__ unsigned short lds_a[2 * 128 * 64];
  __shared__ unsigned short lds_b[1 * 128 * 64];
  int bx = blockIdx.x;
  if (bx < 1024) {
    int s = (bx & 7) * 128 + (bx >> 3);          // XCD swizzle over 1024
    int mt = s >> 2, nt_ = s & 3;
    gemm8_body<4, false>(lds_a, lds_b, xb, wqt, bq, qfrag, nullptr, nullptr,
                         32768, 512, 512, 512, 512, mt * 128, nt_ * 128, 0, 0);
  } else {
    int b2 = bx - 1024;
    int mt = b2 >> 3, nt_ = b2 & 7;
    gemm8_body<2, false>(lds_a, lds_b, xln, wkvt, bkv, nullptr, kfrag, vfrag,
                         2048, 1024, 512, 512, 512, mt * 128, nt_ * 128, 0, 0);
  }
}

// ---------------- LayerNorm + split-K(8) reduction + bias, one wave per row ----------------
__global__ __launch_bounds__(64) void ln_kernel(
    const float* __restrict__ part, const float* __restrict__ bsr,
    const float* __restrict__ gamma, const float* __restrict__ beta,
    unsigned short* __restrict__ xln) {
  const int row = blockIdx.x, lane = threadIdx.x;
  float vv[8];
  #pragma unroll
  for (int j = 0; j < 8; ++j) vv[j] = bsr[lane * 8 + j];
  #pragma unroll
  for (int p = 0; p < 8; ++p) {
    const float* pp = part + ((size_t)p * 2048 + row) * 512 + lane * 8;
    float4 a0 = *(const float4*)pp;
    float4 a1 = *(const float4*)(pp + 4);
    vv[0] += a0.x; vv[1] += a0.y; vv[2] += a0.z; vv[3] += a0.w;
    vv[4] += a1.x; vv[5] += a1.y; vv[6] += a1.z; vv[7] += a1.w;
  }
  float s = 0.f, s2 = 0.f;
  #pragma unroll
  for (int j = 0; j < 8; ++j) { s += vv[j]; s2 += vv[j] * vv[j]; }
  #pragma unroll
  for (int m_ = 1; m_ < 64; m_ <<= 1) { s += __shfl_xor(s, m_); s2 += __shfl_xor(s2, m_); }
  float mean = s * (1.f / 512.f);
  float var = s2 * (1.f / 512.f) - mean * mean;
  float inv = rsqrtf(var + 1e-5f);
  #pragma unroll
  for (int j = 0; j < 8; ++j) {
    int c = lane * 8 + j;
    xln[(size_t)row * 512 + c] = f2bf((vv[j] - mean) * inv * gamma[c] + beta[c]);
  }
}

// ---------------- fused attention: flat 2048 blocks, XCD-chunked mapping ----------------
__global__ __launch_bounds__(512, 4) void attn_kernel(
    const unsigned short* __restrict__ qfrag, const unsigned short* __restrict__ kfrag,
    const unsigned short* __restrict__ vfrag, unsigned short* __restrict__ aout) {
  __shared__ unsigned short k_lds[16384];   // [t(16)][half(2)][lane(64)][8]
  __shared__ unsigned short v_lds[16384];   // [n(4)][ks(8)][lane(64)][8]
  const int tid = threadIdx.x, lane = tid & 63, w = tid >> 6;
  const int l15 = lane & 15;
  const int bid = blockIdx.x;
  const int s_ = (bid & 7) * 256 + (bid >> 3);   // XCD-chunked (2048 % 8 == 0)
  const int bh = s_ >> 5;                        // 0..63
  const int qblk = s_ & 31;                      // 0..31
  const int b = bh >> 3, h = bh & 7;
  const char* kb_ = (const char*)(kfrag + (size_t)bh * 16384);
  const char* vb_ = (const char*)(vfrag + (size_t)bh * 16384);
  #pragma unroll
  for (int r = 0; r < 4; ++r) {
    gload16(kb_ + r * 8192 + tid * 16, (char*)k_lds + r * 8192 + w * 1024);
    gload16(vb_ + r * 8192 + tid * 16, (char*)v_lds + r * 8192 + w * 1024);
  }
  const int qt = qblk * 8 + w;
  const unsigned short* qbase = qfrag + (size_t)bh * 262144 + (size_t)qt * 1024;
  bf16x8 qf0 = *(const bf16x8*)(qbase + lane * 8);
  bf16x8 qf1 = *(const bf16x8*)(qbase + 512 + lane * 8);
  __syncthreads();

  // swapped QK^T: st[t] holds S2[k = t*16 + lhi*4 + r][q = l15]  (log2-domain)
  f32x4 st[16];
  #pragma unroll
  for (int t = 0; t < 16; ++t) {
    bf16x8 kf0 = *(const bf16x8*)&k_lds[t * 1024 + lane * 8];
    bf16x8 kf1 = *(const bf16x8*)&k_lds[t * 1024 + 512 + lane * 8];
    f32x4 a = {0.f, 0.f, 0.f, 0.f};
    a = MFMA16(kf0, qf0, a);
    a = MFMA16(kf1, qf1, a);
    st[t] = a;
  }

  // no-max softmax: p = 2^s2 ; sum over k (in-lane 64 + 2 cross-group shfl)
  float sum = 0.f;
  unsigned pk2[16][2];
  #pragma unroll
  for (int t = 0; t < 16; ++t) {
    float p0 = fast_exp2(st[t][0]), p1 = fast_exp2(st[t][1]);
    float p2 = fast_exp2(st[t][2]), p3 = fast_exp2(st[t][3]);
    sum += (p0 + p1) + (p2 + p3);
    unsigned r0, r1;
    asm("v_cvt_pk_bf16_f32 %0, %1, %2" : "=v"(r0) : "v"(p0), "v"(p1));
    asm("v_cvt_pk_bf16_f32 %0, %1, %2" : "=v"(r1) : "v"(p2), "v"(p3));
    pk2[t][0] = r0; pk2[t][1] = r1;
  }
  sum += __shfl_xor(sum, 16);
  sum += __shfl_xor(sum, 32);
  float invs = 1.f / sum;   // for q = l15 (lane-local for swapped-PV output)

  // redistribute P into A/B-fragment layout (verified shfl path);
  // PV as mfma(V, P) -> O[d][q=l15]
  const int lhi_ = lane >> 4;
  const int srcA = l15 + (((2 * lhi_) & 3) << 4);
  const int srcB = l15 + (((2 * lhi_ + 1) & 3) << 4);
  const bool hi2 = lhi_ >= 2;
  f32x4 o[4] = {};
  #pragma unroll
  for (int ks = 0; ks < 8; ++ks) {
    union { unsigned u[4]; bf16x8 v; } pu;
    unsigned A0 = __shfl(pk2[2 * ks][0], srcA),     A0b = __shfl(pk2[2 * ks][1], srcA);
    unsigned A1 = __shfl(pk2[2 * ks + 1][0], srcA), A1b = __shfl(pk2[2 * ks + 1][1], srcA);
    unsigned B0 = __shfl(pk2[2 * ks][0], srcB),     B0b = __shfl(pk2[2 * ks][1], srcB);
    unsigned B1 = __shfl(pk2[2 * ks + 1][0], srcB), B1b = __shfl(pk2[2 * ks + 1][1], srcB);
    pu.u[0] = hi2 ? A1 : A0;  pu.u[1] = hi2 ? A1b : A0b;
    pu.u[2] = hi2 ? B1 : B0;  pu.u[3] = hi2 ? B1b : B0b;
    #pragma unroll
    for (int n = 0; n < 4; ++n) {
      bf16x8 vf = *(const bf16x8*)&v_lds[(n * 8 + ks) * 512 + lane * 8];
      o[n] = MFMA16(vf, pu.v, o[n]);   // A=V (row=d), B=P (col=q) -> O[d][q]
    }
  }

  const int q0 = qblk * 128;
  const int lhi = lane >> 4;
  #pragma unroll
  for (int n = 0; n < 4; ++n) {
    float a0 = o[n][0] * invs, a1 = o[n][1] * invs;
    float a2 = o[n][2] * invs, a3 = o[n][3] * invs;
    unsigned w0, w1;
    asm("v_cvt_pk_bf16_f32 %0, %1, %2" : "=v"(w0) : "v"(a0), "v"(a1));
    asm("v_cvt_pk_bf16_f32 %0, %1, %2" : "=v"(w1) : "v"(a2), "v"(a3));
    u32x2 pr; pr[0] = w0; pr[1] = w1;
    size_t base = (size_t)(b * 4096 + q0 + w * 16 + l15) * 512 + h * 64 + n * 16 + lhi * 4;
    *(u32x2*)(aout + base) = pr;
  }
}

// ---------------- launch ----------------
extern "C" void kernel_launch(void* const* d_in, const int* in_sizes, int n_in,
                              void* d_out, int out_size, void* d_ws, size_t ws_size,
                              hipStream_t stream) {
  const float* x     = (const float*)d_in[0];
  const float* Wq    = (const float*)d_in[1];
  const float* bq    = (const float*)d_in[2];
  const float* Wkv   = (const float*)d_in[3];
  const float* bkv   = (const float*)d_in[4];
  const float* Wp    = (const float*)d_in[5];
  const float* bp    = (const float*)d_in[6];
  const float* Wsr   = (const float*)d_in[7];
  const float* bsr   = (const float*)d_in[8];
  const float* gamma = (const float*)d_in[9];
  const float* beta  = (const float*)d_in[10];

  char* ws = (char*)d_ws;
  unsigned short* xb    = (unsigned short*)(ws + 0);          // 32 MB (later: aout)
  float*          part  = (float*)(ws + 33554432);            // 32 MB (later: qfrag)
  unsigned short* qfrag = (unsigned short*)(ws + 33554432);
  unsigned short* wqt   = (unsigned short*)(ws + 67108864);   // 512 KB
  unsigned short* wkvt  = (unsigned short*)(ws + 67633152);   // 1 MB
  unsigned short* wpt   = (unsigned short*)(ws + 68681728);   // 512 KB
  unsigned short* wsrt  = (unsigned short*)(ws + 69206016);   // 8 MB
  unsigned short* xln   = (unsigned short*)(ws + 77594624);   // 2 MB
  unsigned short* kfrag = (unsigned short*)(ws + 79691776);   // 2 MB
  unsigned short* vfrag = (unsigned short*)(ws + 81788928);   // 2 MB
  unsigned short* aout  = xb;

  // pack x + all weight transposes (coalesced via LDS tiles), one dispatch
  pack_all<<<17152, 256, 0, stream>>>(x, Wq, Wkv, Wp, Wsr, xb, wqt, wkvt, wpt, wsrt);
  // SR conv as gathered GEMM (A-dbuf/B-single, 3 blk/CU), split-K=8
  gemm8<3, true, true><<<dim3(16, 4, 8), 512, 0, stream>>>(
      xb, wsrt, nullptr, part, nullptr, nullptr, 2048, 512, 8192, 512, 1024);
  // LN fused with split-K(8) reduce + conv bias
  ln_kernel<<<2048, 64, 0, stream>>>(part, bsr, gamma, beta, xln);
  // fused Q-proj + KV-proj (Q scaled by 0.125*log2e)
  proj_fused<<<1152, 512, 0, stream>>>(xb, wqt, bq, qfrag, xln, wkvt, bkv, kfrag, vfrag);
  attn_kernel<<<2048, 512, 0, stream>>>(qfrag, kfrag, vfrag, aout);
  // output projection, XCD-swizzled
  gemm8<0, false, true><<<dim3(256, 4, 1), 512, 0, stream>>>(
      aout, wpt, bp, (float*)d_out, nullptr, nullptr, 32768, 512, 512, 512, 512);
}

// Round 19
// 153.667 us; speedup vs baseline: 1.0049x; 1.0049x over previous
//
#include <hip/hip_runtime.h>
#include <stdint.h>

typedef __attribute__((ext_vector_type(8))) short bf16x8;
typedef __attribute__((ext_vector_type(4))) float f32x4;
typedef __attribute__((ext_vector_type(2))) unsigned u32x2;

#define MFMA16(a,b,c) __builtin_amdgcn_mfma_f32_16x16x32_bf16(a,b,c,0,0,0)

typedef const __attribute__((address_space(1))) void GV;
typedef __attribute__((address_space(3))) void LV;

static __device__ __forceinline__ void gload16(const void* g, void* l) {
  __builtin_amdgcn_global_load_lds((GV*)g, (LV*)l, 16, 0, 0);
}

static __device__ __forceinline__ unsigned short f2bf(float f) {
  union { float f; unsigned u; } x; x.f = f;
  unsigned r = x.u + 0x7FFFu + ((x.u >> 16) & 1u);
  return (unsigned short)(r >> 16);
}

static __device__ __forceinline__ float fast_exp2(float x) {
#if __has_builtin(__builtin_amdgcn_exp2f)
  return __builtin_amdgcn_exp2f(x);
#else
  return __expf(x * 0.6931471805599453f);
#endif
}

// ---------------- pack: x -> bf16, weights -> transposed bf16 (all coalesced) ----------------
__global__ __launch_bounds__(256) void pack_all(
    const float* __restrict__ x, const float* __restrict__ Wq,
    const float* __restrict__ Wkv, const float* __restrict__ Wp,
    const float* __restrict__ Wsr,
    unsigned short* __restrict__ xb, unsigned short* __restrict__ wqt,
    unsigned short* __restrict__ wkvt, unsigned short* __restrict__ wpt,
    unsigned short* __restrict__ wsrt) {
  const int tid = threadIdx.x;
  int bid = blockIdx.x;
  if (bid < 16384) {                      // x -> bf16, 4 floats/thread
    int i = bid * 256 + tid;
    float4 v = ((const float4*)x)[i];
    unsigned a0 = f2bf(v.x), a1 = f2bf(v.y), a2 = f2bf(v.z), a3 = f2bf(v.w);
    uint2 pk; pk.x = a0 | (a1 << 16); pk.y = a2 | (a3 << 16);
    ((uint2*)xb)[i] = pk;
    return;
  }
  bid -= 16384;
  __shared__ float lsm[8704];             // 64x65 tiles / 512x17 for Wsr

  auto wtile = [&](const float* __restrict__ W, unsigned short* __restrict__ out,
                   int ldw, int tr, int tc) {
    int k0 = tr * 64, n0 = tc * 64;
    #pragma unroll
    for (int i = 0; i < 16; ++i) {
      int idx = i * 256 + tid; int r = idx >> 6, c = idx & 63;
      lsm[r * 65 + c] = W[(size_t)(k0 + r) * ldw + n0 + c];
    }
    __syncthreads();
    #pragma unroll
    for (int i = 0; i < 16; ++i) {
      int idx = i * 256 + tid; int n = idx >> 6, k = idx & 63;
      out[(size_t)(n0 + n) * 512 + k0 + k] = f2bf(lsm[k * 65 + n]);
    }
  };

  if (bid < 64) { wtile(Wq, wqt, 512, bid >> 3, bid & 7); return; }
  bid -= 64;
  if (bid < 128) { wtile(Wkv, wkvt, 1024, bid >> 4, bid & 15); return; }
  bid -= 128;
  if (bid < 64) { wtile(Wp, wpt, 512, bid >> 3, bid & 7); return; }
  bid -= 64;
  // Wsr: per oc, transpose [ic(512)][r12(16)] -> wsrt[oc][r12][ic]
  int oc = bid;
  #pragma unroll
  for (int i = 0; i < 32; ++i) {
    int idx = i * 256 + tid;
    lsm[(idx >> 4) * 17 + (idx & 15)] = Wsr[(size_t)oc * 8192 + idx];
  }
  __syncthreads();
  #pragma unroll
  for (int i = 0; i < 32; ++i) {
    int idx = i * 256 + tid;                      // idx = r12*512 + ic
    int ic = idx & 511, r12 = idx >> 9;
    wsrt[(size_t)oc * 8192 + idx] = f2bf(lsm[ic * 17 + r12]);
  }
}

// ---------------- 8-wave GEMM body: 128x128 tile, dbuf + counted vmcnt ----------------
// 512 threads = 8 waves (2M x 4N); per-wave 64x32, acc[4][2] = 32 AGPRs.
// T5 setprio REMOVED: null-to-negative on lockstep 2-barrier GEMMs (m190).
// MODE 0: fp32 out (+bias); MODE 2: K/V scatter; MODE 3: conv partial;
// MODE 4: Q fragment scatter (+bias, * 0.125*log2e)
template<int MODE, bool CONV>
static __device__ __forceinline__ void gemm8_body(
    unsigned short* lds_a, unsigned short* lds_b,
    const unsigned short* __restrict__ A, const unsigned short* __restrict__ Bt,
    const float* __restrict__ bias, void* __restrict__ outp,
    unsigned short* __restrict__ out_k, unsigned short* __restrict__ out_v,
    int M, int N, int K, int lda, int Ksub, int m0, int n0, int kbeg, int zslice) {
  constexpr int BK = 64;
  constexpr int ABYTES = 128 * BK * 2;     // 16 KB per buffer per operand
  const int tid = threadIdx.x;
  const int lane = tid & 63, w = tid >> 6;
  const int wr = w >> 2, wc = w & 3;       // 2 x 4 wave grid
  const int l15 = lane & 15, lhi = lane >> 4;
  const int xmask = (l15 & 7) << 4;        // read-side byte swizzle
  const int smask = ((tid >> 3) & 7) << 3; // stage-side element swizzle

  f32x4 acc[4][2] = {};

  auto stage = [&](int buf, int k0) {
    #pragma unroll
    for (int r = 0; r < 2; ++r) {
      int o = r * 8192 + tid * 16;
      int row = o >> 7;
      int kc = (((o & 127) >> 1)) ^ smask;
      const unsigned short* src;
      if constexpr (CONV) {
        int m = m0 + row;
        int bb = m >> 8, pix = m & 255;
        int oh = pix >> 4, ow = pix & 15;
        int r12 = k0 >> 9;
        int icc = (k0 & 511) + kc;
        int r1 = r12 >> 2, r2 = r12 & 3;
        int nn = (oh * 4 + r1) * 64 + ow * 4 + r2;
        src = A + ((size_t)(bb * 4096 + nn)) * 512 + icc;
      } else {
        src = A + (size_t)(m0 + row) * lda + k0 + kc;
      }
      gload16(src, (char*)lds_a + buf * ABYTES + r * 8192 + w * 1024);
    }
    #pragma unroll
    for (int r = 0; r < 2; ++r) {
      int o = r * 8192 + tid * 16;
      int row = o >> 7;
      int kc = (((o & 127) >> 1)) ^ smask;
      const unsigned short* src = Bt + (size_t)(n0 + row) * K + k0 + kc;
      gload16(src, (char*)lds_b + buf * ABYTES + r * 8192 + w * 1024);
    }
  };

  auto compute = [&](int buf) {
    const char* pa = (const char*)lds_a + buf * ABYTES;
    const char* pb = (const char*)lds_b + buf * ABYTES;
    #pragma unroll
    for (int kk = 0; kk < BK; kk += 32) {
      bf16x8 af[4], bfr[2];
      #pragma unroll
      for (int m = 0; m < 4; ++m)
        af[m] = *(const bf16x8*)(pa + (wr * 64 + m * 16 + l15) * 128
                                 + (((kk << 1) + (lhi << 4)) ^ xmask));
      #pragma unroll
      for (int n = 0; n < 2; ++n)
        bfr[n] = *(const bf16x8*)(pb + (wc * 32 + n * 16 + l15) * 128
                                  + (((kk << 1) + (lhi << 4)) ^ xmask));
      #pragma unroll
      for (int m = 0; m < 4; ++m)
        #pragma unroll
        for (int n = 0; n < 2; ++n)
          acc[m][n] = MFMA16(af[m], bfr[n], acc[m][n]);
    }
  };

  const int nsteps = Ksub / BK;
  stage(0, kbeg);
  int buf = 0;
  for (int t = 0; t < nsteps; ++t) {
    if (t + 1 < nsteps) {
      stage(buf ^ 1, kbeg + (t + 1) * BK);
      asm volatile("s_waitcnt vmcnt(4)" ::: "memory");  // stage(t) landed; t+1 in flight
    } else {
      asm volatile("s_waitcnt vmcnt(0)" ::: "memory");
    }
    __builtin_amdgcn_s_barrier();
    compute(buf);
    __builtin_amdgcn_s_barrier();
    buf ^= 1;
  }

  #pragma unroll
  for (int m = 0; m < 4; ++m) {
    #pragma unroll
    for (int n = 0; n < 2; ++n) {
      #pragma unroll
      for (int r = 0; r < 4; ++r) {
        int gm = m0 + wr * 64 + m * 16 + lhi * 4 + r;
        int gn = n0 + wc * 32 + n * 16 + l15;
        if constexpr (MODE == 0) {
          ((float*)outp)[(size_t)gm * N + gn] = acc[m][n][r] + bias[gn];
        } else if constexpr (MODE == 3) {
          ((float*)outp)[((size_t)zslice * M + gm) * N + gn] = acc[m][n][r];
        } else if constexpr (MODE == 4) {
          float v = (acc[m][n][r] + bias[gn]) * 0.18033688011112042f;  // 0.125*log2(e)
          int b_ = gm >> 12, n_ = gm & 4095;
          int hh = gn >> 6, d = gn & 63;
          int qt = n_ >> 4, half = d >> 5, dd = d & 31;
          int ln = (n_ & 15) | ((dd >> 3) << 4);
          ((unsigned short*)outp)[(size_t)(b_ * 8 + hh) * 262144 +
              (qt * 2 + half) * 512 + ln * 8 + (d & 7)] = f2bf(v);
        } else {  // MODE 2: K/V scatter
          float v = acc[m][n][r] + bias[gn];
          unsigned short bv = f2bf(v);
          int bb = gm >> 8, nr = gm & 255;
          if (gn < 512) {
            int hh = gn >> 6, d = gn & 63;
            int t_ = nr >> 4, half = d >> 5, dd = d & 31;
            int ln = (nr & 15) | ((dd >> 3) << 4);
            out_k[(size_t)(bb * 8 + hh) * 16384 +
                  (t_ * 2 + half) * 512 + ln * 8 + (d & 7)] = bv;
          } else {
            int c = gn - 512;
            int hh = c >> 6, d = c & 63;
            int nn = d >> 4, cl = d & 15;
            int ks = nr >> 5, lh = (nr >> 3) & 3;
            out_v[(size_t)(bb * 8 + hh) * 16384 +
                  (nn * 8 + ks) * 512 + (cl | (lh << 4)) * 8 + (nr & 7)] = bv;
          }
        }
      }
    }
  }
}

// standalone 8-wave GEMM kernel, optional XCD swizzle
template<int MODE, bool CONV, bool SWZ>
__global__ __launch_bounds__(512, 4) void gemm8(
    const unsigned short* __restrict__ A, const unsigned short* __restrict__ Bt,
    const float* __restrict__ bias, void* __restrict__ outp,
    unsigned short* __restrict__ out_k, unsigned short* __restrict__ out_v,
    int M, int N, int K, int lda, int Ksub) {
  __shared__ unsigned short lds_a[2 * 128 * 64];
  __shared__ unsigned short lds_b[2 * 128 * 64];
  int mt, nt_;
  if constexpr (SWZ) {
    int lin = blockIdx.x + blockIdx.y * gridDim.x;
    int nwg = gridDim.x * gridDim.y;
    int cpx = nwg >> 3;
    int s = (lin & 7) * cpx + (lin >> 3);
    int gdy = gridDim.y;
    mt = s / gdy; nt_ = s - mt * gdy;
  } else { mt = blockIdx.x; nt_ = blockIdx.y; }
  gemm8_body<MODE, CONV>(lds_a, lds_b, A, Bt, bias, outp, out_k, out_v,
                         M, N, K, lda, Ksub, mt * 128, nt_ * 128,
                         blockIdx.z * Ksub, blockIdx.z);
}

// fused Q-proj (1024 blocks, swizzled) + KV-proj (128 blocks), 8-wave
__global__ __launch_bounds__(512, 4) void proj_fused(
    const unsigned short* __restrict__ xb, const unsigned short* __restrict__ wqt,
    const float* __restrict__ bq, unsigned short* __restrict__ qfrag,
    const unsigned short* __restrict__ xln, const unsigned short* __restrict__ wkvt,
    const float* __restrict__ bkv, unsigned short* __restrict__ kfrag,
    unsigned short* __restrict__ vfrag) {
  __shared__ unsigned short lds_a[2 * 128 * 64];
  __shared__ unsigned short lds_b[2 * 128 * 64];
  int bx = blockIdx.x;
  if (bx < 1024) {
    int s = (bx & 7) * 128 + (bx >> 3);          // XCD swizzle over 1024
    int mt = s >> 2, nt_ = s & 3;
    gemm8_body<4, false>(lds_a, lds_b, xb, wqt, bq, qfrag, nullptr, nullptr,
                         32768, 512, 512, 512, 512, mt * 128, nt_ * 128, 0, 0);
  } else {
    int b2 = bx - 1024;
    int mt = b2 >> 3, nt_ = b2 & 7;
    gemm8_body<2, false>(lds_a, lds_b, xln, wkvt, bkv, nullptr, kfrag, vfrag,
                         2048, 1024, 512, 512, 512, mt * 128, nt_ * 128, 0, 0);
  }
}

// ---------------- LayerNorm + split-K(8) reduction + bias, one wave per row ----------------
__global__ __launch_bounds__(64) void ln_kernel(
    const float* __restrict__ part, const float* __restrict__ bsr,
    const float* __restrict__ gamma, const float* __restrict__ beta,
    unsigned short* __restrict__ xln) {
  const int row = blockIdx.x, lane = threadIdx.x;
  float vv[8];
  #pragma unroll
  for (int j = 0; j < 8; ++j) vv[j] = bsr[lane * 8 + j];
  #pragma unroll
  for (int p = 0; p < 8; ++p) {
    const float* pp = part + ((size_t)p * 2048 + row) * 512 + lane * 8;
    float4 a0 = *(const float4*)pp;
    float4 a1 = *(const float4*)(pp + 4);
    vv[0] += a0.x; vv[1] += a0.y; vv[2] += a0.z; vv[3] += a0.w;
    vv[4] += a1.x; vv[5] += a1.y; vv[6] += a1.z; vv[7] += a1.w;
  }
  float s = 0.f, s2 = 0.f;
  #pragma unroll
  for (int j = 0; j < 8; ++j) { s += vv[j]; s2 += vv[j] * vv[j]; }
  #pragma unroll
  for (int m_ = 1; m_ < 64; m_ <<= 1) { s += __shfl_xor(s, m_); s2 += __shfl_xor(s2, m_); }
  float mean = s * (1.f / 512.f);
  float var = s2 * (1.f / 512.f) - mean * mean;
  float inv = rsqrtf(var + 1e-5f);
  #pragma unroll
  for (int j = 0; j < 8; ++j) {
    int c = lane * 8 + j;
    xln[(size_t)row * 512 + c] = f2bf((vv[j] - mean) * inv * gamma[c] + beta[c]);
  }
}

// ---------------- fused attention: flat 2048 blocks, XCD-chunked mapping ----------------
__global__ __launch_bounds__(512, 4) void attn_kernel(
    const unsigned short* __restrict__ qfrag, const unsigned short* __restrict__ kfrag,
    const unsigned short* __restrict__ vfrag, unsigned short* __restrict__ aout) {
  __shared__ unsigned short k_lds[16384];   // [t(16)][half(2)][lane(64)][8]
  __shared__ unsigned short v_lds[16384];   // [n(4)][ks(8)][lane(64)][8]
  const int tid = threadIdx.x, lane = tid & 63, w = tid >> 6;
  const int l15 = lane & 15;
  const int bid = blockIdx.x;
  const int s_ = (bid & 7) * 256 + (bid >> 3);   // XCD-chunked (2048 % 8 == 0)
  const int bh = s_ >> 5;                        // 0..63
  const int qblk = s_ & 31;                      // 0..31
  const int b = bh >> 3, h = bh & 7;
  const char* kb_ = (const char*)(kfrag + (size_t)bh * 16384);
  const char* vb_ = (const char*)(vfrag + (size_t)bh * 16384);
  #pragma unroll
  for (int r = 0; r < 4; ++r) {
    gload16(kb_ + r * 8192 + tid * 16, (char*)k_lds + r * 8192 + w * 1024);
    gload16(vb_ + r * 8192 + tid * 16, (char*)v_lds + r * 8192 + w * 1024);
  }
  const int qt = qblk * 8 + w;
  const unsigned short* qbase = qfrag + (size_t)bh * 262144 + (size_t)qt * 1024;
  bf16x8 qf0 = *(const bf16x8*)(qbase + lane * 8);
  bf16x8 qf1 = *(const bf16x8*)(qbase + 512 + lane * 8);
  __syncthreads();

  // swapped QK^T: st[t] holds S2[k = t*16 + lhi*4 + r][q = l15]  (log2-domain)
  f32x4 st[16];
  #pragma unroll
  for (int t = 0; t < 16; ++t) {
    bf16x8 kf0 = *(const bf16x8*)&k_lds[t * 1024 + lane * 8];
    bf16x8 kf1 = *(const bf16x8*)&k_lds[t * 1024 + 512 + lane * 8];
    f32x4 a = {0.f, 0.f, 0.f, 0.f};
    a = MFMA16(kf0, qf0, a);
    a = MFMA16(kf1, qf1, a);
    st[t] = a;
  }

  // no-max softmax: p = 2^s2 ; sum over k (in-lane 64 + 2 cross-group shfl)
  float sum = 0.f;
  unsigned pk2[16][2];
  #pragma unroll
  for (int t = 0; t < 16; ++t) {
    float p0 = fast_exp2(st[t][0]), p1 = fast_exp2(st[t][1]);
    float p2 = fast_exp2(st[t][2]), p3 = fast_exp2(st[t][3]);
    sum += (p0 + p1) + (p2 + p3);
    unsigned r0, r1;
    asm("v_cvt_pk_bf16_f32 %0, %1, %2" : "=v"(r0) : "v"(p0), "v"(p1));
    asm("v_cvt_pk_bf16_f32 %0, %1, %2" : "=v"(r1) : "v"(p2), "v"(p3));
    pk2[t][0] = r0; pk2[t][1] = r1;
  }
  sum += __shfl_xor(sum, 16);
  sum += __shfl_xor(sum, 32);
  float invs = 1.f / sum;   // for q = l15 (lane-local for swapped-PV output)

  // redistribute P into A/B-fragment layout (verified shfl path);
  // PV as mfma(V, P) -> O[d][q=l15]
  const int lhi_ = lane >> 4;
  const int srcA = l15 + (((2 * lhi_) & 3) << 4);
  const int srcB = l15 + (((2 * lhi_ + 1) & 3) << 4);
  const bool hi2 = lhi_ >= 2;
  f32x4 o[4] = {};
  #pragma unroll
  for (int ks = 0; ks < 8; ++ks) {
    union { unsigned u[4]; bf16x8 v; } pu;
    unsigned A0 = __shfl(pk2[2 * ks][0], srcA),     A0b = __shfl(pk2[2 * ks][1], srcA);
    unsigned A1 = __shfl(pk2[2 * ks + 1][0], srcA), A1b = __shfl(pk2[2 * ks + 1][1], srcA);
    unsigned B0 = __shfl(pk2[2 * ks][0], srcB),     B0b = __shfl(pk2[2 * ks][1], srcB);
    unsigned B1 = __shfl(pk2[2 * ks + 1][0], srcB), B1b = __shfl(pk2[2 * ks + 1][1], srcB);
    pu.u[0] = hi2 ? A1 : A0;  pu.u[1] = hi2 ? A1b : A0b;
    pu.u[2] = hi2 ? B1 : B0;  pu.u[3] = hi2 ? B1b : B0b;
    #pragma unroll
    for (int n = 0; n < 4; ++n) {
      bf16x8 vf = *(const bf16x8*)&v_lds[(n * 8 + ks) * 512 + lane * 8];
      o[n] = MFMA16(vf, pu.v, o[n]);   // A=V (row=d), B=P (col=q) -> O[d][q]
    }
  }

  const int q0 = qblk * 128;
  const int lhi = lane >> 4;
  #pragma unroll
  for (int n = 0; n < 4; ++n) {
    float a0 = o[n][0] * invs, a1 = o[n][1] * invs;
    float a2 = o[n][2] * invs, a3 = o[n][3] * invs;
    unsigned w0, w1;
    asm("v_cvt_pk_bf16_f32 %0, %1, %2" : "=v"(w0) : "v"(a0), "v"(a1));
    asm("v_cvt_pk_bf16_f32 %0, %1, %2" : "=v"(w1) : "v"(a2), "v"(a3));
    u32x2 pr; pr[0] = w0; pr[1] = w1;
    size_t base = (size_t)(b * 4096 + q0 + w * 16 + l15) * 512 + h * 64 + n * 16 + lhi * 4;
    *(u32x2*)(aout + base) = pr;
  }
}

// ---------------- launch ----------------
extern "C" void kernel_launch(void* const* d_in, const int* in_sizes, int n_in,
                              void* d_out, int out_size, void* d_ws, size_t ws_size,
                              hipStream_t stream) {
  const float* x     = (const float*)d_in[0];
  const float* Wq    = (const float*)d_in[1];
  const float* bq    = (const float*)d_in[2];
  const float* Wkv   = (const float*)d_in[3];
  const float* bkv   = (const float*)d_in[4];
  const float* Wp    = (const float*)d_in[5];
  const float* bp    = (const float*)d_in[6];
  const float* Wsr   = (const float*)d_in[7];
  const float* bsr   = (const float*)d_in[8];
  const float* gamma = (const float*)d_in[9];
  const float* beta  = (const float*)d_in[10];

  char* ws = (char*)d_ws;
  unsigned short* xb    = (unsigned short*)(ws + 0);          // 32 MB (later: aout)
  float*          part  = (float*)(ws + 33554432);            // 32 MB (later: qfrag)
  unsigned short* qfrag = (unsigned short*)(ws + 33554432);
  unsigned short* wqt   = (unsigned short*)(ws + 67108864);   // 512 KB
  unsigned short* wkvt  = (unsigned short*)(ws + 67633152);   // 1 MB
  unsigned short* wpt   = (unsigned short*)(ws + 68681728);   // 512 KB
  unsigned short* wsrt  = (unsigned short*)(ws + 69206016);   // 8 MB
  unsigned short* xln   = (unsigned short*)(ws + 77594624);   // 2 MB
  unsigned short* kfrag = (unsigned short*)(ws + 79691776);   // 2 MB
  unsigned short* vfrag = (unsigned short*)(ws + 81788928);   // 2 MB
  unsigned short* aout  = xb;

  // pack x + all weight transposes (coalesced via LDS tiles), one dispatch
  pack_all<<<17152, 256, 0, stream>>>(x, Wq, Wkv, Wp, Wsr, xb, wqt, wkvt, wpt, wsrt);
  // SR conv as gathered GEMM (8-wave dbuf), split-K=8 -> fp32 partials
  gemm8<3, true, true><<<dim3(16, 4, 8), 512, 0, stream>>>(
      xb, wsrt, nullptr, part, nullptr, nullptr, 2048, 512, 8192, 512, 1024);
  // LN fused with split-K(8) reduce + conv bias
  ln_kernel<<<2048, 64, 0, stream>>>(part, bsr, gamma, beta, xln);
  // fused Q-proj + KV-proj (8-wave dbuf; Q scaled by 0.125*log2e)
  proj_fused<<<1152, 512, 0, stream>>>(xb, wqt, bq, qfrag, xln, wkvt, bkv, kfrag, vfrag);
  attn_kernel<<<2048, 512, 0, stream>>>(qfrag, kfrag, vfrag, aout);
  // output projection (8-wave dbuf), XCD-swizzled
  gemm8<0, false, true><<<dim3(256, 4, 1), 512, 0, stream>>>(
      aout, wpt, bp, (float*)d_out, nullptr, nullptr, 32768, 512, 512, 512, 512);
}

// Round 20
// 152.477 us; speedup vs baseline: 1.0128x; 1.0078x over previous
//
#include <hip/hip_runtime.h>
#include <stdint.h>

typedef __attribute__((ext_vector_type(8))) short bf16x8;
typedef __attribute__((ext_vector_type(4))) float f32x4;
typedef __attribute__((ext_vector_type(2))) unsigned u32x2;

#define MFMA16(a,b,c) __builtin_amdgcn_mfma_f32_16x16x32_bf16(a,b,c,0,0,0)

typedef const __attribute__((address_space(1))) void GV;
typedef __attribute__((address_space(3))) void LV;

static __device__ __forceinline__ void gload16(const void* g, void* l) {
  __builtin_amdgcn_global_load_lds((GV*)g, (LV*)l, 16, 0, 0);
}

static __device__ __forceinline__ unsigned short f2bf(float f) {
  union { float f; unsigned u; } x; x.f = f;
  unsigned r = x.u + 0x7FFFu + ((x.u >> 16) & 1u);
  return (unsigned short)(r >> 16);
}

static __device__ __forceinline__ float fast_exp2(float x) {
#if __has_builtin(__builtin_amdgcn_exp2f)
  return __builtin_amdgcn_exp2f(x);
#else
  return __expf(x * 0.6931471805599453f);
#endif
}

// ---------------- pack: x -> bf16, weights -> transposed bf16 (all coalesced) ----------------
__global__ __launch_bounds__(256) void pack_all(
    const float* __restrict__ x, const float* __restrict__ Wq,
    const float* __restrict__ Wkv, const float* __restrict__ Wp,
    const float* __restrict__ Wsr,
    unsigned short* __restrict__ xb, unsigned short* __restrict__ wqt,
    unsigned short* __restrict__ wkvt, unsigned short* __restrict__ wpt,
    unsigned short* __restrict__ wsrt) {
  const int tid = threadIdx.x;
  int bid = blockIdx.x;
  if (bid < 16384) {                      // x -> bf16, 4 floats/thread
    int i = bid * 256 + tid;
    float4 v = ((const float4*)x)[i];
    unsigned a0 = f2bf(v.x), a1 = f2bf(v.y), a2 = f2bf(v.z), a3 = f2bf(v.w);
    uint2 pk; pk.x = a0 | (a1 << 16); pk.y = a2 | (a3 << 16);
    ((uint2*)xb)[i] = pk;
    return;
  }
  bid -= 16384;
  __shared__ float lsm[8704];             // 64x65 tiles / 512x17 for Wsr

  auto wtile = [&](const float* __restrict__ W, unsigned short* __restrict__ out,
                   int ldw, int tr, int tc) {
    int k0 = tr * 64, n0 = tc * 64;
    #pragma unroll
    for (int i = 0; i < 16; ++i) {
      int idx = i * 256 + tid; int r = idx >> 6, c = idx & 63;
      lsm[r * 65 + c] = W[(size_t)(k0 + r) * ldw + n0 + c];
    }
    __syncthreads();
    #pragma unroll
    for (int i = 0; i < 16; ++i) {
      int idx = i * 256 + tid; int n = idx >> 6, k = idx & 63;
      out[(size_t)(n0 + n) * 512 + k0 + k] = f2bf(lsm[k * 65 + n]);
    }
  };

  if (bid < 64) { wtile(Wq, wqt, 512, bid >> 3, bid & 7); return; }
  bid -= 64;
  if (bid < 128) { wtile(Wkv, wkvt, 1024, bid >> 4, bid & 15); return; }
  bid -= 128;
  if (bid < 64) { wtile(Wp, wpt, 512, bid >> 3, bid & 7); return; }
  bid -= 64;
  // Wsr: per oc, transpose [ic(512)][r12(16)] -> wsrt[oc][r12][ic]
  int oc = bid;
  #pragma unroll
  for (int i = 0; i < 32; ++i) {
    int idx = i * 256 + tid;
    lsm[(idx >> 4) * 17 + (idx & 15)] = Wsr[(size_t)oc * 8192 + idx];
  }
  __syncthreads();
  #pragma unroll
  for (int i = 0; i < 32; ++i) {
    int idx = i * 256 + tid;                      // idx = r12*512 + ic
    int ic = idx & 511, r12 = idx >> 9;
    wsrt[(size_t)oc * 8192 + idx] = f2bf(lsm[ic * 17 + r12]);
  }
}

// ---------------- 8-wave GEMM body: 128x128 tile, dbuf + counted vmcnt ----------------
// 512 threads = 8 waves (2M x 4N); per-wave 64x32, acc[4][2] = 32 AGPRs.
// MODE 0: fp32 out (+bias); MODE 2: K/V scatter; MODE 3: conv partial;
// MODE 4: Q fragment scatter (+bias, * 0.125*log2e)
template<int MODE, bool CONV>
static __device__ __forceinline__ void gemm8_body(
    unsigned short* lds_a, unsigned short* lds_b,
    const unsigned short* __restrict__ A, const unsigned short* __restrict__ Bt,
    const float* __restrict__ bias, void* __restrict__ outp,
    unsigned short* __restrict__ out_k, unsigned short* __restrict__ out_v,
    int M, int N, int K, int lda, int Ksub, int m0, int n0, int kbeg, int zslice) {
  constexpr int BK = 64;
  constexpr int ABYTES = 128 * BK * 2;     // 16 KB per buffer per operand
  const int tid = threadIdx.x;
  const int lane = tid & 63, w = tid >> 6;
  const int wr = w >> 2, wc = w & 3;       // 2 x 4 wave grid
  const int l15 = lane & 15, lhi = lane >> 4;
  const int xmask = (l15 & 7) << 4;        // read-side byte swizzle
  const int smask = ((tid >> 3) & 7) << 3; // stage-side element swizzle

  f32x4 acc[4][2] = {};

  auto stage = [&](int buf, int k0) {
    #pragma unroll
    for (int r = 0; r < 2; ++r) {
      int o = r * 8192 + tid * 16;
      int row = o >> 7;
      int kc = (((o & 127) >> 1)) ^ smask;
      const unsigned short* src;
      if constexpr (CONV) {
        int m = m0 + row;
        int bb = m >> 8, pix = m & 255;
        int oh = pix >> 4, ow = pix & 15;
        int r12 = k0 >> 9;
        int icc = (k0 & 511) + kc;
        int r1 = r12 >> 2, r2 = r12 & 3;
        int nn = (oh * 4 + r1) * 64 + ow * 4 + r2;
        src = A + ((size_t)(bb * 4096 + nn)) * 512 + icc;
      } else {
        src = A + (size_t)(m0 + row) * lda + k0 + kc;
      }
      gload16(src, (char*)lds_a + buf * ABYTES + r * 8192 + w * 1024);
    }
    #pragma unroll
    for (int r = 0; r < 2; ++r) {
      int o = r * 8192 + tid * 16;
      int row = o >> 7;
      int kc = (((o & 127) >> 1)) ^ smask;
      const unsigned short* src = Bt + (size_t)(n0 + row) * K + k0 + kc;
      gload16(src, (char*)lds_b + buf * ABYTES + r * 8192 + w * 1024);
    }
  };

  auto compute = [&](int buf) {
    const char* pa = (const char*)lds_a + buf * ABYTES;
    const char* pb = (const char*)lds_b + buf * ABYTES;
    #pragma unroll
    for (int kk = 0; kk < BK; kk += 32) {
      bf16x8 af[4], bfr[2];
      #pragma unroll
      for (int m = 0; m < 4; ++m)
        af[m] = *(const bf16x8*)(pa + (wr * 64 + m * 16 + l15) * 128
                                 + (((kk << 1) + (lhi << 4)) ^ xmask));
      #pragma unroll
      for (int n = 0; n < 2; ++n)
        bfr[n] = *(const bf16x8*)(pb + (wc * 32 + n * 16 + l15) * 128
                                  + (((kk << 1) + (lhi << 4)) ^ xmask));
      __builtin_amdgcn_s_setprio(1);
      #pragma unroll
      for (int m = 0; m < 4; ++m)
        #pragma unroll
        for (int n = 0; n < 2; ++n)
          acc[m][n] = MFMA16(af[m], bfr[n], acc[m][n]);
      __builtin_amdgcn_s_setprio(0);
    }
  };

  const int nsteps = Ksub / BK;
  stage(0, kbeg);
  int buf = 0;
  for (int t = 0; t < nsteps; ++t) {
    if (t + 1 < nsteps) {
      stage(buf ^ 1, kbeg + (t + 1) * BK);
      asm volatile("s_waitcnt vmcnt(4)" ::: "memory");  // stage(t) landed; t+1 in flight
    } else {
      asm volatile("s_waitcnt vmcnt(0)" ::: "memory");
    }
    __builtin_amdgcn_s_barrier();
    compute(buf);
    __builtin_amdgcn_s_barrier();
    buf ^= 1;
  }

  #pragma unroll
  for (int m = 0; m < 4; ++m) {
    #pragma unroll
    for (int n = 0; n < 2; ++n) {
      #pragma unroll
      for (int r = 0; r < 4; ++r) {
        int gm = m0 + wr * 64 + m * 16 + lhi * 4 + r;
        int gn = n0 + wc * 32 + n * 16 + l15;
        if constexpr (MODE == 0) {
          ((float*)outp)[(size_t)gm * N + gn] = acc[m][n][r] + bias[gn];
        } else if constexpr (MODE == 3) {
          ((float*)outp)[((size_t)zslice * M + gm) * N + gn] = acc[m][n][r];
        } else if constexpr (MODE == 4) {
          float v = (acc[m][n][r] + bias[gn]) * 0.18033688011112042f;  // 0.125*log2(e)
          int b_ = gm >> 12, n_ = gm & 4095;
          int hh = gn >> 6, d = gn & 63;
          int qt = n_ >> 4, half = d >> 5, dd = d & 31;
          int ln = (n_ & 15) | ((dd >> 3) << 4);
          ((unsigned short*)outp)[(size_t)(b_ * 8 + hh) * 262144 +
              (qt * 2 + half) * 512 + ln * 8 + (d & 7)] = f2bf(v);
        } else {  // MODE 2: K/V scatter
          float v = acc[m][n][r] + bias[gn];
          unsigned short bv = f2bf(v);
          int bb = gm >> 8, nr = gm & 255;
          if (gn < 512) {
            int hh = gn >> 6, d = gn & 63;
            int t_ = nr >> 4, half = d >> 5, dd = d & 31;
            int ln = (nr & 15) | ((dd >> 3) << 4);
            out_k[(size_t)(bb * 8 + hh) * 16384 +
                  (t_ * 2 + half) * 512 + ln * 8 + (d & 7)] = bv;
          } else {
            int c = gn - 512;
            int hh = c >> 6, d = c & 63;
            int nn = d >> 4, cl = d & 15;
            int ks = nr >> 5, lh = (nr >> 3) & 3;
            out_v[(size_t)(bb * 8 + hh) * 16384 +
                  (nn * 8 + ks) * 512 + (cl | (lh << 4)) * 8 + (nr & 7)] = bv;
          }
        }
      }
    }
  }
}

// standalone 8-wave GEMM kernel, optional XCD swizzle
template<int MODE, bool CONV, bool SWZ>
__global__ __launch_bounds__(512, 4) void gemm8(
    const unsigned short* __restrict__ A, const unsigned short* __restrict__ Bt,
    const float* __restrict__ bias, void* __restrict__ outp,
    unsigned short* __restrict__ out_k, unsigned short* __restrict__ out_v,
    int M, int N, int K, int lda, int Ksub) {
  __shared__ unsigned short lds_a[2 * 128 * 64];
  __shared__ unsigned short lds_b[2 * 128 * 64];
  int mt, nt_;
  if constexpr (SWZ) {
    int lin = blockIdx.x + blockIdx.y * gridDim.x;
    int nwg = gridDim.x * gridDim.y;
    int cpx = nwg >> 3;
    int s = (lin & 7) * cpx + (lin >> 3);
    int gdy = gridDim.y;
    mt = s / gdy; nt_ = s - mt * gdy;
  } else { mt = blockIdx.x; nt_ = blockIdx.y; }
  gemm8_body<MODE, CONV>(lds_a, lds_b, A, Bt, bias, outp, out_k, out_v,
                         M, N, K, lda, Ksub, mt * 128, nt_ * 128,
                         blockIdx.z * Ksub, blockIdx.z);
}

// fused Q-proj (1024 blocks, swizzled) + KV-proj (128 blocks), 8-wave
__global__ __launch_bounds__(512, 4) void proj_fused(
    const unsigned short* __restrict__ xb, const unsigned short* __restrict__ wqt,
    const float* __restrict__ bq, unsigned short* __restrict__ qfrag,
    const unsigned short* __restrict__ xln, const unsigned short* __restrict__ wkvt,
    const float* __restrict__ bkv, unsigned short* __restrict__ kfrag,
    unsigned short* __restrict__ vfrag) {
  __shared__ unsigned short lds_a[2 * 128 * 64];
  __shared__ unsigned short lds_b[2 * 128 * 64];
  int bx = blockIdx.x;
  if (bx < 1024) {
    int s = (bx & 7) * 128 + (bx >> 3);          // XCD swizzle over 1024
    int mt = s >> 2, nt_ = s & 3;
    gemm8_body<4, false>(lds_a, lds_b, xb, wqt, bq, qfrag, nullptr, nullptr,
                         32768, 512, 512, 512, 512, mt * 128, nt_ * 128, 0, 0);
  } else {
    int b2 = bx - 1024;
    int mt = b2 >> 3, nt_ = b2 & 7;
    gemm8_body<2, false>(lds_a, lds_b, xln, wkvt, bkv, nullptr, kfrag, vfrag,
                         2048, 1024, 512, 512, 512, mt * 128, nt_ * 128, 0, 0);
  }
}

// ---------------- LayerNorm + split-K(8) reduction + bias, one wave per row ----------------
__global__ __launch_bounds__(64) void ln_kernel(
    const float* __restrict__ part, const float* __restrict__ bsr,
    const float* __restrict__ gamma, const float* __restrict__ beta,
    unsigned short* __restrict__ xln) {
  const int row = blockIdx.x, lane = threadIdx.x;
  float vv[8];
  #pragma unroll
  for (int j = 0; j < 8; ++j) vv[j] = bsr[lane * 8 + j];
  #pragma unroll
  for (int p = 0; p < 8; ++p) {
    const float* pp = part + ((size_t)p * 2048 + row) * 512 + lane * 8;
    float4 a0 = *(const float4*)pp;
    float4 a1 = *(const float4*)(pp + 4);
    vv[0] += a0.x; vv[1] += a0.y; vv[2] += a0.z; vv[3] += a0.w;
    vv[4] += a1.x; vv[5] += a1.y; vv[6] += a1.z; vv[7] += a1.w;
  }
  float s = 0.f, s2 = 0.f;
  #pragma unroll
  for (int j = 0; j < 8; ++j) { s += vv[j]; s2 += vv[j] * vv[j]; }
  #pragma unroll
  for (int m_ = 1; m_ < 64; m_ <<= 1) { s += __shfl_xor(s, m_); s2 += __shfl_xor(s2, m_); }
  float mean = s * (1.f / 512.f);
  float var = s2 * (1.f / 512.f) - mean * mean;
  float inv = rsqrtf(var + 1e-5f);
  #pragma unroll
  for (int j = 0; j < 8; ++j) {
    int c = lane * 8 + j;
    xln[(size_t)row * 512 + c] = f2bf((vv[j] - mean) * inv * gamma[c] + beta[c]);
  }
}

// ---------------- fused attention: flat 2048 blocks, XCD-chunked mapping ----------------
__global__ __launch_bounds__(512, 4) void attn_kernel(
    const unsigned short* __restrict__ qfrag, const unsigned short* __restrict__ kfrag,
    const unsigned short* __restrict__ vfrag, unsigned short* __restrict__ aout) {
  __shared__ unsigned short k_lds[16384];   // [t(16)][half(2)][lane(64)][8]
  __shared__ unsigned short v_lds[16384];   // [n(4)][ks(8)][lane(64)][8]
  const int tid = threadIdx.x, lane = tid & 63, w = tid >> 6;
  const int l15 = lane & 15;
  const int bid = blockIdx.x;
  const int s_ = (bid & 7) * 256 + (bid >> 3);   // XCD-chunked (2048 % 8 == 0)
  const int bh = s_ >> 5;                        // 0..63
  const int qblk = s_ & 31;                      // 0..31
  const int b = bh >> 3, h = bh & 7;
  const char* kb_ = (const char*)(kfrag + (size_t)bh * 16384);
  const char* vb_ = (const char*)(vfrag + (size_t)bh * 16384);
  #pragma unroll
  for (int r = 0; r < 4; ++r) {
    gload16(kb_ + r * 8192 + tid * 16, (char*)k_lds + r * 8192 + w * 1024);
    gload16(vb_ + r * 8192 + tid * 16, (char*)v_lds + r * 8192 + w * 1024);
  }
  const int qt = qblk * 8 + w;
  const unsigned short* qbase = qfrag + (size_t)bh * 262144 + (size_t)qt * 1024;
  bf16x8 qf0 = *(const bf16x8*)(qbase + lane * 8);
  bf16x8 qf1 = *(const bf16x8*)(qbase + 512 + lane * 8);
  __syncthreads();

  // swapped QK^T: st[t] holds S2[k = t*16 + lhi*4 + r][q = l15]  (log2-domain)
  f32x4 st[16];
  #pragma unroll
  for (int t = 0; t < 16; ++t) {
    bf16x8 kf0 = *(const bf16x8*)&k_lds[t * 1024 + lane * 8];
    bf16x8 kf1 = *(const bf16x8*)&k_lds[t * 1024 + 512 + lane * 8];
    f32x4 a = {0.f, 0.f, 0.f, 0.f};
    a = MFMA16(kf0, qf0, a);
    a = MFMA16(kf1, qf1, a);
    st[t] = a;
  }

  // no-max softmax: p = 2^s2 ; sum over k (in-lane 64 + 2 cross-group shfl)
  float sum = 0.f;
  unsigned pk2[16][2];
  #pragma unroll
  for (int t = 0; t < 16; ++t) {
    float p0 = fast_exp2(st[t][0]), p1 = fast_exp2(st[t][1]);
    float p2 = fast_exp2(st[t][2]), p3 = fast_exp2(st[t][3]);
    sum += (p0 + p1) + (p2 + p3);
    unsigned r0, r1;
    asm("v_cvt_pk_bf16_f32 %0, %1, %2" : "=v"(r0) : "v"(p0), "v"(p1));
    asm("v_cvt_pk_bf16_f32 %0, %1, %2" : "=v"(r1) : "v"(p2), "v"(p3));
    pk2[t][0] = r0; pk2[t][1] = r1;
  }
  sum += __shfl_xor(sum, 16);
  sum += __shfl_xor(sum, 32);
  float invs = 1.f / sum;   // for q = l15 (lane-local for swapped-PV output)

  // redistribute P into A/B-fragment layout (verified shfl path);
  // PV as mfma(V, P) -> O[d][q=l15]
  const int lhi_ = lane >> 4;
  const int srcA = l15 + (((2 * lhi_) & 3) << 4);
  const int srcB = l15 + (((2 * lhi_ + 1) & 3) << 4);
  const bool hi2 = lhi_ >= 2;
  f32x4 o[4] = {};
  #pragma unroll
  for (int ks = 0; ks < 8; ++ks) {
    union { unsigned u[4]; bf16x8 v; } pu;
    unsigned A0 = __shfl(pk2[2 * ks][0], srcA),     A0b = __shfl(pk2[2 * ks][1], srcA);
    unsigned A1 = __shfl(pk2[2 * ks + 1][0], srcA), A1b = __shfl(pk2[2 * ks + 1][1], srcA);
    unsigned B0 = __shfl(pk2[2 * ks][0], srcB),     B0b = __shfl(pk2[2 * ks][1], srcB);
    unsigned B1 = __shfl(pk2[2 * ks + 1][0], srcB), B1b = __shfl(pk2[2 * ks + 1][1], srcB);
    pu.u[0] = hi2 ? A1 : A0;  pu.u[1] = hi2 ? A1b : A0b;
    pu.u[2] = hi2 ? B1 : B0;  pu.u[3] = hi2 ? B1b : B0b;
    #pragma unroll
    for (int n = 0; n < 4; ++n) {
      bf16x8 vf = *(const bf16x8*)&v_lds[(n * 8 + ks) * 512 + lane * 8];
      o[n] = MFMA16(vf, pu.v, o[n]);   // A=V (row=d), B=P (col=q) -> O[d][q]
    }
  }

  const int q0 = qblk * 128;
  const int lhi = lane >> 4;
  #pragma unroll
  for (int n = 0; n < 4; ++n) {
    float a0 = o[n][0] * invs, a1 = o[n][1] * invs;
    float a2 = o[n][2] * invs, a3 = o[n][3] * invs;
    unsigned w0, w1;
    asm("v_cvt_pk_bf16_f32 %0, %1, %2" : "=v"(w0) : "v"(a0), "v"(a1));
    asm("v_cvt_pk_bf16_f32 %0, %1, %2" : "=v"(w1) : "v"(a2), "v"(a3));
    u32x2 pr; pr[0] = w0; pr[1] = w1;
    size_t base = (size_t)(b * 4096 + q0 + w * 16 + l15) * 512 + h * 64 + n * 16 + lhi * 4;
    *(u32x2*)(aout + base) = pr;
  }
}

// ---------------- launch ----------------
extern "C" void kernel_launch(void* const* d_in, const int* in_sizes, int n_in,
                              void* d_out, int out_size, void* d_ws, size_t ws_size,
                              hipStream_t stream) {
  const float* x     = (const float*)d_in[0];
  const float* Wq    = (const float*)d_in[1];
  const float* bq    = (const float*)d_in[2];
  const float* Wkv   = (const float*)d_in[3];
  const float* bkv   = (const float*)d_in[4];
  const float* Wp    = (const float*)d_in[5];
  const float* bp    = (const float*)d_in[6];
  const float* Wsr   = (const float*)d_in[7];
  const float* bsr   = (const float*)d_in[8];
  const float* gamma = (const float*)d_in[9];
  const float* beta  = (const float*)d_in[10];

  char* ws = (char*)d_ws;
  unsigned short* xb    = (unsigned short*)(ws + 0);          // 32 MB (later: aout)
  float*          part  = (float*)(ws + 33554432);            // 32 MB (later: qfrag)
  unsigned short* qfrag = (unsigned short*)(ws + 33554432);
  unsigned short* wqt   = (unsigned short*)(ws + 67108864);   // 512 KB
  unsigned short* wkvt  = (unsigned short*)(ws + 67633152);   // 1 MB
  unsigned short* wpt   = (unsigned short*)(ws + 68681728);   // 512 KB
  unsigned short* wsrt  = (unsigned short*)(ws + 69206016);   // 8 MB
  unsigned short* xln   = (unsigned short*)(ws + 77594624);   // 2 MB
  unsigned short* kfrag = (unsigned short*)(ws + 79691776);   // 2 MB
  unsigned short* vfrag = (unsigned short*)(ws + 81788928);   // 2 MB
  unsigned short* aout  = xb;

  // pack x + all weight transposes (coalesced via LDS tiles), one dispatch
  pack_all<<<17152, 256, 0, stream>>>(x, Wq, Wkv, Wp, Wsr, xb, wqt, wkvt, wpt, wsrt);
  // SR conv as gathered GEMM (8-wave dbuf), split-K=8 -> fp32 partials
  gemm8<3, true, true><<<dim3(16, 4, 8), 512, 0, stream>>>(
      xb, wsrt, nullptr, part, nullptr, nullptr, 2048, 512, 8192, 512, 1024);
  // LN fused with split-K(8) reduce + conv bias
  ln_kernel<<<2048, 64, 0, stream>>>(part, bsr, gamma, beta, xln);
  // fused Q-proj + KV-proj (8-wave dbuf; Q scaled by 0.125*log2e)
  proj_fused<<<1152, 512, 0, stream>>>(xb, wqt, bq, qfrag, xln, wkvt, bkv, kfrag, vfrag);
  attn_kernel<<<2048, 512, 0, stream>>>(qfrag, kfrag, vfrag, aout);
  // output projection (8-wave dbuf), XCD-swizzled
  gemm8<0, false, true><<<dim3(256, 4, 1), 512, 0, stream>>>(
      aout, wpt, bp, (float*)d_out, nullptr, nullptr, 32768, 512, 512, 512, 512);
}

// Round 21
// 150.105 us; speedup vs baseline: 1.0288x; 1.0158x over previous
//
#include <hip/hip_runtime.h>
#include <stdint.h>

typedef __attribute__((ext_vector_type(8))) short bf16x8;
typedef __attribute__((ext_vector_type(4))) float f32x4;
typedef __attribute__((ext_vector_type(2))) unsigned u32x2;

#define MFMA16(a,b,c) __builtin_amdgcn_mfma_f32_16x16x32_bf16(a,b,c,0,0,0)

typedef const __attribute__((address_space(1))) void GV;
typedef __attribute__((address_space(3))) void LV;

static __device__ __forceinline__ void gload16(const void* g, void* l) {
  __builtin_amdgcn_global_load_lds((GV*)g, (LV*)l, 16, 0, 0);
}

static __device__ __forceinline__ unsigned short f2bf(float f) {
  union { float f; unsigned u; } x; x.f = f;
  unsigned r = x.u + 0x7FFFu + ((x.u >> 16) & 1u);
  return (unsigned short)(r >> 16);
}

static __device__ __forceinline__ float fast_exp2(float x) {
#if __has_builtin(__builtin_amdgcn_exp2f)
  return __builtin_amdgcn_exp2f(x);
#else
  return __expf(x * 0.6931471805599453f);
#endif
}

// ---------------- pack: x -> bf16, weights -> transposed bf16 (all coalesced) ----------------
__global__ __launch_bounds__(256) void pack_all(
    const float* __restrict__ x, const float* __restrict__ Wq,
    const float* __restrict__ Wkv, const float* __restrict__ Wp,
    const float* __restrict__ Wsr,
    unsigned short* __restrict__ xb, unsigned short* __restrict__ wqt,
    unsigned short* __restrict__ wkvt, unsigned short* __restrict__ wpt,
    unsigned short* __restrict__ wsrt) {
  const int tid = threadIdx.x;
  int bid = blockIdx.x;
  if (bid < 16384) {                      // x -> bf16, 4 floats/thread
    int i = bid * 256 + tid;
    float4 v = ((const float4*)x)[i];
    unsigned a0 = f2bf(v.x), a1 = f2bf(v.y), a2 = f2bf(v.z), a3 = f2bf(v.w);
    uint2 pk; pk.x = a0 | (a1 << 16); pk.y = a2 | (a3 << 16);
    ((uint2*)xb)[i] = pk;
    return;
  }
  bid -= 16384;
  __shared__ float lsm[8704];             // 64x65 tiles / 512x17 for Wsr

  auto wtile = [&](const float* __restrict__ W, unsigned short* __restrict__ out,
                   int ldw, int tr, int tc) {
    int k0 = tr * 64, n0 = tc * 64;
    #pragma unroll
    for (int i = 0; i < 16; ++i) {
      int idx = i * 256 + tid; int r = idx >> 6, c = idx & 63;
      lsm[r * 65 + c] = W[(size_t)(k0 + r) * ldw + n0 + c];
    }
    __syncthreads();
    #pragma unroll
    for (int i = 0; i < 16; ++i) {
      int idx = i * 256 + tid; int n = idx >> 6, k = idx & 63;
      out[(size_t)(n0 + n) * 512 + k0 + k] = f2bf(lsm[k * 65 + n]);
    }
  };

  if (bid < 64) { wtile(Wq, wqt, 512, bid >> 3, bid & 7); return; }
  bid -= 64;
  if (bid < 128) { wtile(Wkv, wkvt, 1024, bid >> 4, bid & 15); return; }
  bid -= 128;
  if (bid < 64) { wtile(Wp, wpt, 512, bid >> 3, bid & 7); return; }
  bid -= 64;
  // Wsr: per oc, transpose [ic(512)][r12(16)] -> wsrt[oc][r12][ic]
  int oc = bid;
  #pragma unroll
  for (int i = 0; i < 32; ++i) {
    int idx = i * 256 + tid;
    lsm[(idx >> 4) * 17 + (idx & 15)] = Wsr[(size_t)oc * 8192 + idx];
  }
  __syncthreads();
  #pragma unroll
  for (int i = 0; i < 32; ++i) {
    int idx = i * 256 + tid;                      // idx = r12*512 + ic
    int ic = idx & 511, r12 = idx >> 9;
    wsrt[(size_t)oc * 8192 + idx] = f2bf(lsm[ic * 17 + r12]);
  }
}

// ---------------- 8-wave GEMM body: 128x128 tile, dbuf + counted vmcnt ----------------
// 512 threads = 8 waves (2M x 4N); per-wave 64x32, acc[4][2] = 32 AGPRs.
// MODE 0: fp32 out (+bias); MODE 2: K/V scatter; MODE 3: conv partial;
// MODE 4: Q fragment scatter (+bias, * 0.125*log2e)
template<int MODE, bool CONV>
static __device__ __forceinline__ void gemm8_body(
    unsigned short* lds_a, unsigned short* lds_b,
    const unsigned short* __restrict__ A, const unsigned short* __restrict__ Bt,
    const float* __restrict__ bias, void* __restrict__ outp,
    unsigned short* __restrict__ out_k, unsigned short* __restrict__ out_v,
    int M, int N, int K, int lda, int Ksub, int m0, int n0, int kbeg, int zslice) {
  constexpr int BK = 64;
  constexpr int ABYTES = 128 * BK * 2;     // 16 KB per buffer per operand
  const int tid = threadIdx.x;
  const int lane = tid & 63, w = tid >> 6;
  const int wr = w >> 2, wc = w & 3;       // 2 x 4 wave grid
  const int l15 = lane & 15, lhi = lane >> 4;
  const int xmask = (l15 & 7) << 4;        // read-side byte swizzle
  const int smask = ((tid >> 3) & 7) << 3; // stage-side element swizzle

  f32x4 acc[4][2] = {};

  auto stage = [&](int buf, int k0) {
    #pragma unroll
    for (int r = 0; r < 2; ++r) {
      int o = r * 8192 + tid * 16;
      int row = o >> 7;
      int kc = (((o & 127) >> 1)) ^ smask;
      const unsigned short* src;
      if constexpr (CONV) {
        int m = m0 + row;
        int bb = m >> 8, pix = m & 255;
        int oh = pix >> 4, ow = pix & 15;
        int r12 = k0 >> 9;
        int icc = (k0 & 511) + kc;
        int r1 = r12 >> 2, r2 = r12 & 3;
        int nn = (oh * 4 + r1) * 64 + ow * 4 + r2;
        src = A + ((size_t)(bb * 4096 + nn)) * 512 + icc;
      } else {
        src = A + (size_t)(m0 + row) * lda + k0 + kc;
      }
      gload16(src, (char*)lds_a + buf * ABYTES + r * 8192 + w * 1024);
    }
    #pragma unroll
    for (int r = 0; r < 2; ++r) {
      int o = r * 8192 + tid * 16;
      int row = o >> 7;
      int kc = (((o & 127) >> 1)) ^ smask;
      const unsigned short* src = Bt + (size_t)(n0 + row) * K + k0 + kc;
      gload16(src, (char*)lds_b + buf * ABYTES + r * 8192 + w * 1024);
    }
  };

  auto compute = [&](int buf) {
    const char* pa = (const char*)lds_a + buf * ABYTES;
    const char* pb = (const char*)lds_b + buf * ABYTES;
    #pragma unroll
    for (int kk = 0; kk < BK; kk += 32) {
      bf16x8 af[4], bfr[2];
      #pragma unroll
      for (int m = 0; m < 4; ++m)
        af[m] = *(const bf16x8*)(pa + (wr * 64 + m * 16 + l15) * 128
                                 + (((kk << 1) + (lhi << 4)) ^ xmask));
      #pragma unroll
      for (int n = 0; n < 2; ++n)
        bfr[n] = *(const bf16x8*)(pb + (wc * 32 + n * 16 + l15) * 128
                                  + (((kk << 1) + (lhi << 4)) ^ xmask));
      __builtin_amdgcn_s_setprio(1);
      #pragma unroll
      for (int m = 0; m < 4; ++m)
        #pragma unroll
        for (int n = 0; n < 2; ++n)
          acc[m][n] = MFMA16(af[m], bfr[n], acc[m][n]);
      __builtin_amdgcn_s_setprio(0);
    }
  };

  const int nsteps = Ksub / BK;
  stage(0, kbeg);
  int buf = 0;
  for (int t = 0; t < nsteps; ++t) {
    if (t + 1 < nsteps) {
      stage(buf ^ 1, kbeg + (t + 1) * BK);
      asm volatile("s_waitcnt vmcnt(4)" ::: "memory");  // stage(t) landed; t+1 in flight
    } else {
      asm volatile("s_waitcnt vmcnt(0)" ::: "memory");
    }
    __builtin_amdgcn_s_barrier();
    compute(buf);
    __builtin_amdgcn_s_barrier();
    buf ^= 1;
  }

  #pragma unroll
  for (int m = 0; m < 4; ++m) {
    #pragma unroll
    for (int n = 0; n < 2; ++n) {
      #pragma unroll
      for (int r = 0; r < 4; ++r) {
        int gm = m0 + wr * 64 + m * 16 + lhi * 4 + r;
        int gn = n0 + wc * 32 + n * 16 + l15;
        if constexpr (MODE == 0) {
          ((float*)outp)[(size_t)gm * N + gn] = acc[m][n][r] + bias[gn];
        } else if constexpr (MODE == 3) {
          ((float*)outp)[((size_t)zslice * M + gm) * N + gn] = acc[m][n][r];
        } else if constexpr (MODE == 4) {
          float v = (acc[m][n][r] + bias[gn]) * 0.18033688011112042f;  // 0.125*log2(e)
          int b_ = gm >> 12, n_ = gm & 4095;
          int hh = gn >> 6, d = gn & 63;
          int qt = n_ >> 4, half = d >> 5, dd = d & 31;
          int ln = (n_ & 15) | ((dd >> 3) << 4);
          ((unsigned short*)outp)[(size_t)(b_ * 8 + hh) * 262144 +
              (qt * 2 + half) * 512 + ln * 8 + (d & 7)] = f2bf(v);
        } else {  // MODE 2: K/V scatter
          float v = acc[m][n][r] + bias[gn];
          unsigned short bv = f2bf(v);
          int bb = gm >> 8, nr = gm & 255;
          if (gn < 512) {
            int hh = gn >> 6, d = gn & 63;
            int t_ = nr >> 4, half = d >> 5, dd = d & 31;
            int ln = (nr & 15) | ((dd >> 3) << 4);
            out_k[(size_t)(bb * 8 + hh) * 16384 +
                  (t_ * 2 + half) * 512 + ln * 8 + (d & 7)] = bv;
          } else {
            int c = gn - 512;
            int hh = c >> 6, d = c & 63;
            int nn = d >> 4, cl = d & 15;
            int ks = nr >> 5, lh = (nr >> 3) & 3;
            out_v[(size_t)(bb * 8 + hh) * 16384 +
                  (nn * 8 + ks) * 512 + (cl | (lh << 4)) * 8 + (nr & 7)] = bv;
          }
        }
      }
    }
  }
}

// standalone 8-wave GEMM kernel, optional XCD swizzle
template<int MODE, bool CONV, bool SWZ>
__global__ __launch_bounds__(512, 4) void gemm8(
    const unsigned short* __restrict__ A, const unsigned short* __restrict__ Bt,
    const float* __restrict__ bias, void* __restrict__ outp,
    unsigned short* __restrict__ out_k, unsigned short* __restrict__ out_v,
    int M, int N, int K, int lda, int Ksub) {
  __shared__ unsigned short lds_a[2 * 128 * 64];
  __shared__ unsigned short lds_b[2 * 128 * 64];
  int mt, nt_;
  if constexpr (SWZ) {
    int lin = blockIdx.x + blockIdx.y * gridDim.x;
    int nwg = gridDim.x * gridDim.y;
    int cpx = nwg >> 3;
    int s = (lin & 7) * cpx + (lin >> 3);
    int gdy = gridDim.y;
    mt = s / gdy; nt_ = s - mt * gdy;
  } else { mt = blockIdx.x; nt_ = blockIdx.y; }
  gemm8_body<MODE, CONV>(lds_a, lds_b, A, Bt, bias, outp, out_k, out_v,
                         M, N, K, lda, Ksub, mt * 128, nt_ * 128,
                         blockIdx.z * Ksub, blockIdx.z);
}

// fused Q-proj (1024 blocks, swizzled) + KV-proj (128 blocks), 8-wave
__global__ __launch_bounds__(512, 4) void proj_fused(
    const unsigned short* __restrict__ xb, const unsigned short* __restrict__ wqt,
    const float* __restrict__ bq, unsigned short* __restrict__ qfrag,
    const unsigned short* __restrict__ xln, const unsigned short* __restrict__ wkvt,
    const float* __restrict__ bkv, unsigned short* __restrict__ kfrag,
    unsigned short* __restrict__ vfrag) {
  __shared__ unsigned short lds_a[2 * 128 * 64];
  __shared__ unsigned short lds_b[2 * 128 * 64];
  int bx = blockIdx.x;
  if (bx < 1024) {
    int s = (bx & 7) * 128 + (bx >> 3);          // XCD swizzle over 1024
    int mt = s >> 2, nt_ = s & 3;
    gemm8_body<4, false>(lds_a, lds_b, xb, wqt, bq, qfrag, nullptr, nullptr,
                         32768, 512, 512, 512, 512, mt * 128, nt_ * 128, 0, 0);
  } else {
    int b2 = bx - 1024;
    int mt = b2 >> 3, nt_ = b2 & 7;
    gemm8_body<2, false>(lds_a, lds_b, xln, wkvt, bkv, nullptr, kfrag, vfrag,
                         2048, 1024, 512, 512, 512, mt * 128, nt_ * 128, 0, 0);
  }
}

// ---------------- LayerNorm + split-K(8) reduction + bias, 4 rows/block ----------------
__global__ __launch_bounds__(256) void ln_kernel(
    const float* __restrict__ part, const float* __restrict__ bsr,
    const float* __restrict__ gamma, const float* __restrict__ beta,
    unsigned short* __restrict__ xln) {
  const int row = blockIdx.x * 4 + (threadIdx.x >> 6);
  const int lane = threadIdx.x & 63;
  float vv[8];
  #pragma unroll
  for (int j = 0; j < 8; ++j) vv[j] = bsr[lane * 8 + j];
  #pragma unroll
  for (int p = 0; p < 8; ++p) {
    const float* pp = part + ((size_t)p * 2048 + row) * 512 + lane * 8;
    float4 a0 = *(const float4*)pp;
    float4 a1 = *(const float4*)(pp + 4);
    vv[0] += a0.x; vv[1] += a0.y; vv[2] += a0.z; vv[3] += a0.w;
    vv[4] += a1.x; vv[5] += a1.y; vv[6] += a1.z; vv[7] += a1.w;
  }
  float s = 0.f, s2 = 0.f;
  #pragma unroll
  for (int j = 0; j < 8; ++j) { s += vv[j]; s2 += vv[j] * vv[j]; }
  #pragma unroll
  for (int m_ = 1; m_ < 64; m_ <<= 1) { s += __shfl_xor(s, m_); s2 += __shfl_xor(s2, m_); }
  float mean = s * (1.f / 512.f);
  float var = s2 * (1.f / 512.f) - mean * mean;
  float inv = rsqrtf(var + 1e-5f);
  #pragma unroll
  for (int j = 0; j < 8; ++j) {
    int c = lane * 8 + j;
    xln[(size_t)row * 512 + c] = f2bf((vv[j] - mean) * inv * gamma[c] + beta[c]);
  }
}

// ---------------- fused attention: flat 2048 blocks, XCD-chunked mapping ----------------
__global__ __launch_bounds__(512, 4) void attn_kernel(
    const unsigned short* __restrict__ qfrag, const unsigned short* __restrict__ kfrag,
    const unsigned short* __restrict__ vfrag, unsigned short* __restrict__ aout) {
  __shared__ unsigned short k_lds[16384];   // [t(16)][half(2)][lane(64)][8]
  __shared__ unsigned short v_lds[16384];   // [n(4)][ks(8)][lane(64)][8]
  const int tid = threadIdx.x, lane = tid & 63, w = tid >> 6;
  const int l15 = lane & 15;
  const int bid = blockIdx.x;
  const int s_ = (bid & 7) * 256 + (bid >> 3);   // XCD-chunked (2048 % 8 == 0)
  const int bh = s_ >> 5;                        // 0..63
  const int qblk = s_ & 31;                      // 0..31
  const int b = bh >> 3, h = bh & 7;
  const char* kb_ = (const char*)(kfrag + (size_t)bh * 16384);
  const char* vb_ = (const char*)(vfrag + (size_t)bh * 16384);
  #pragma unroll
  for (int r = 0; r < 4; ++r) {
    gload16(kb_ + r * 8192 + tid * 16, (char*)k_lds + r * 8192 + w * 1024);
    gload16(vb_ + r * 8192 + tid * 16, (char*)v_lds + r * 8192 + w * 1024);
  }
  const int qt = qblk * 8 + w;
  const unsigned short* qbase = qfrag + (size_t)bh * 262144 + (size_t)qt * 1024;
  bf16x8 qf0 = *(const bf16x8*)(qbase + lane * 8);
  bf16x8 qf1 = *(const bf16x8*)(qbase + 512 + lane * 8);
  __syncthreads();

  // swapped QK^T: st[t] holds S2[k = t*16 + lhi*4 + r][q = l15]  (log2-domain)
  f32x4 st[16];
  #pragma unroll
  for (int t = 0; t < 16; ++t) {
    bf16x8 kf0 = *(const bf16x8*)&k_lds[t * 1024 + lane * 8];
    bf16x8 kf1 = *(const bf16x8*)&k_lds[t * 1024 + 512 + lane * 8];
    f32x4 a = {0.f, 0.f, 0.f, 0.f};
    a = MFMA16(kf0, qf0, a);
    a = MFMA16(kf1, qf1, a);
    st[t] = a;
  }

  // no-max softmax: p = 2^s2 ; sum over k (in-lane 64 + 2 cross-group shfl)
  float sum = 0.f;
  unsigned pk2[16][2];
  #pragma unroll
  for (int t = 0; t < 16; ++t) {
    float p0 = fast_exp2(st[t][0]), p1 = fast_exp2(st[t][1]);
    float p2 = fast_exp2(st[t][2]), p3 = fast_exp2(st[t][3]);
    sum += (p0 + p1) + (p2 + p3);
    unsigned r0, r1;
    asm("v_cvt_pk_bf16_f32 %0, %1, %2" : "=v"(r0) : "v"(p0), "v"(p1));
    asm("v_cvt_pk_bf16_f32 %0, %1, %2" : "=v"(r1) : "v"(p2), "v"(p3));
    pk2[t][0] = r0; pk2[t][1] = r1;
  }
  sum += __shfl_xor(sum, 16);
  sum += __shfl_xor(sum, 32);
  float invs = 1.f / sum;   // for q = l15 (lane-local for swapped-PV output)

  // redistribute P into A/B-fragment layout (verified shfl path);
  // PV as mfma(V, P) -> O[d][q=l15]
  const int lhi_ = lane >> 4;
  const int srcA = l15 + (((2 * lhi_) & 3) << 4);
  const int srcB = l15 + (((2 * lhi_ + 1) & 3) << 4);
  const bool hi2 = lhi_ >= 2;
  f32x4 o[4] = {};
  #pragma unroll
  for (int ks = 0; ks < 8; ++ks) {
    union { unsigned u[4]; bf16x8 v; } pu;
    unsigned A0 = __shfl(pk2[2 * ks][0], srcA),     A0b = __shfl(pk2[2 * ks][1], srcA);
    unsigned A1 = __shfl(pk2[2 * ks + 1][0], srcA), A1b = __shfl(pk2[2 * ks + 1][1], srcA);
    unsigned B0 = __shfl(pk2[2 * ks][0], srcB),     B0b = __shfl(pk2[2 * ks][1], srcB);
    unsigned B1 = __shfl(pk2[2 * ks + 1][0], srcB), B1b = __shfl(pk2[2 * ks + 1][1], srcB);
    pu.u[0] = hi2 ? A1 : A0;  pu.u[1] = hi2 ? A1b : A0b;
    pu.u[2] = hi2 ? B1 : B0;  pu.u[3] = hi2 ? B1b : B0b;
    #pragma unroll
    for (int n = 0; n < 4; ++n) {
      bf16x8 vf = *(const bf16x8*)&v_lds[(n * 8 + ks) * 512 + lane * 8];
      o[n] = MFMA16(vf, pu.v, o[n]);   // A=V (row=d), B=P (col=q) -> O[d][q]
    }
  }

  const int q0 = qblk * 128;
  const int lhi = lane >> 4;
  #pragma unroll
  for (int n = 0; n < 4; ++n) {
    float a0 = o[n][0] * invs, a1 = o[n][1] * invs;
    float a2 = o[n][2] * invs, a3 = o[n][3] * invs;
    unsigned w0, w1;
    asm("v_cvt_pk_bf16_f32 %0, %1, %2" : "=v"(w0) : "v"(a0), "v"(a1));
    asm("v_cvt_pk_bf16_f32 %0, %1, %2" : "=v"(w1) : "v"(a2), "v"(a3));
    u32x2 pr; pr[0] = w0; pr[1] = w1;
    size_t base = (size_t)(b * 4096 + q0 + w * 16 + l15) * 512 + h * 64 + n * 16 + lhi * 4;
    *(u32x2*)(aout + base) = pr;
  }
}

// ---------------- launch ----------------
extern "C" void kernel_launch(void* const* d_in, const int* in_sizes, int n_in,
                              void* d_out, int out_size, void* d_ws, size_t ws_size,
                              hipStream_t stream) {
  const float* x     = (const float*)d_in[0];
  const float* Wq    = (const float*)d_in[1];
  const float* bq    = (const float*)d_in[2];
  const float* Wkv   = (const float*)d_in[3];
  const float* bkv   = (const float*)d_in[4];
  const float* Wp    = (const float*)d_in[5];
  const float* bp    = (const float*)d_in[6];
  const float* Wsr   = (const float*)d_in[7];
  const float* bsr   = (const float*)d_in[8];
  const float* gamma = (const float*)d_in[9];
  const float* beta  = (const float*)d_in[10];

  char* ws = (char*)d_ws;
  unsigned short* xb    = (unsigned short*)(ws + 0);          // 32 MB (later: aout)
  float*          part  = (float*)(ws + 33554432);            // 32 MB (later: qfrag)
  unsigned short* qfrag = (unsigned short*)(ws + 33554432);
  unsigned short* wqt   = (unsigned short*)(ws + 67108864);   // 512 KB
  unsigned short* wkvt  = (unsigned short*)(ws + 67633152);   // 1 MB
  unsigned short* wpt   = (unsigned short*)(ws + 68681728);   // 512 KB
  unsigned short* wsrt  = (unsigned short*)(ws + 69206016);   // 8 MB
  unsigned short* xln   = (unsigned short*)(ws + 77594624);   // 2 MB
  unsigned short* kfrag = (unsigned short*)(ws + 79691776);   // 2 MB
  unsigned short* vfrag = (unsigned short*)(ws + 81788928);   // 2 MB
  unsigned short* aout  = xb;

  // pack x + all weight transposes (coalesced via LDS tiles), one dispatch
  pack_all<<<17152, 256, 0, stream>>>(x, Wq, Wkv, Wp, Wsr, xb, wqt, wkvt, wpt, wsrt);
  // SR conv as gathered GEMM (8-wave dbuf), split-K=8 -> fp32 partials
  gemm8<3, true, true><<<dim3(16, 4, 8), 512, 0, stream>>>(
      xb, wsrt, nullptr, part, nullptr, nullptr, 2048, 512, 8192, 512, 1024);
  // LN fused with split-K(8) reduce + conv bias (4 rows/block)
  ln_kernel<<<512, 256, 0, stream>>>(part, bsr, gamma, beta, xln);
  // fused Q-proj + KV-proj (8-wave dbuf; Q scaled by 0.125*log2e)
  proj_fused<<<1152, 512, 0, stream>>>(xb, wqt, bq, qfrag, xln, wkvt, bkv, kfrag, vfrag);
  attn_kernel<<<2048, 512, 0, stream>>>(qfrag, kfrag, vfrag, aout);
  // output projection (8-wave dbuf), XCD-swizzled
  gemm8<0, false, true><<<dim3(256, 4, 1), 512, 0, stream>>>(
      aout, wpt, bp, (float*)d_out, nullptr, nullptr, 32768, 512, 512, 512, 512);
}